// Round 8
// baseline (472.862 us; speedup 1.0000x reference)
//
#include <hip/hip_runtime.h>
#include <math.h>
#include <stdint.h>

// ---------------------------------------------------------------------------
// KAN forward, split-bf16 MFMA version, round 11: barrier-free K-loop.
//   R10 compute structure kept (512 thr / 8 waves / 128 rows, split-K chunk
//   parity, 32x32x16, product-major ct-groups). NEW: W fragments are read
//   DIRECTLY FROM GLOBAL (L1/L2-served) instead of LDS-staged — W is 4.5 MB,
//   identical for all blocks, and the prep layout makes each fragment a
//   contiguous 16B/lane read. This removes the per-pair __syncthreads that
//   phase-locked all 8 waves into identical [build][MFMA] phases (R7-R10 all
//   clamp at ~121 us with MFMA 3072 + VALU 2670 + stall 2350 strictly
//   ADDITIVE). With no barrier, co-SIMD waves (ks=0/1) drift and the CU
//   scheduler overlaps one wave's MFMA burst with the other's VALU builds
//   (m114 mechanism). The 4 same-parity waves per CU read identical W
//   addresses -> L1 absorbs most re-reads; L2 demand well under ceiling.
//   LDS shrinks to a 64 KB epilogue scratch (2-pass cross-ks reduction).
//   Augmented-K GEMM per layer: K = 9F (8 spline bases + 1 silu per feature).
//   W prefolded, split into bf16 hi/lo pair.
//   3-product split emulation: Ah*Wh + Al*Wh + Ah*Wl  (error ~2^-16 rel).
// ---------------------------------------------------------------------------

#define N_PTS 32768

using short8 = __attribute__((ext_vector_type(8))) short;
using f32x4  = __attribute__((ext_vector_type(4))) float;
using f32x16 = __attribute__((ext_vector_type(16))) float;

union Frag { short8 v; uint32_t u[4]; };

__device__ __forceinline__ uint32_t bf16rne(float f) {
    uint32_t u = __float_as_uint(f);
    return (u + 0x7FFFu + ((u >> 16) & 1u)) >> 16;
}
__device__ __forceinline__ float bf16tof(uint32_t h) { return __uint_as_float(h << 16); }

// pack bf16-trunc(x0) into lo16, bf16-trunc(x1) into hi16 — one v_perm_b32
__device__ __forceinline__ uint32_t pkhi(uint32_t x0, uint32_t x1) {
    return __builtin_amdgcn_perm(x1, x0, 0x07060302u);
}

// ---------------------------------------------------------------------------
// fast uniform cubic B-spline, trunc-split bf16 fragments.
// t = (x+2.2)/0.4 ; i = floor(t) ; slot j nonzero for j = i-3..i with value
// q_{i-j}.  Pair p (slots 2p,2p+1) selected from 5 packed candidates by i-2p.
__device__ __forceinline__ void build_basis_frag(float x, Frag& ah, Frag& al) {
    float t  = (x + 2.2f) * 2.5f;
    float fl = floorf(t);
    int   i  = (int)fl;
    float w  = t - fl;
    float w2 = w * w, w3 = w2 * w;
    const float s = 1.0f / 6.0f;
    float q0 = w3 * s;                                     // d == 0 (j == i)
    float q1 = (-3.f * w3 + 3.f * w2 + 3.f * w + 1.f) * s; // d == 1
    float q2 = (3.f * w3 - 6.f * w2 + 4.f) * s;            // d == 2
    float omw = 1.f - w;
    float q3 = omw * omw * omw * s;                        // d == 3
    uint32_t u0 = __float_as_uint(q0), u1 = __float_as_uint(q1);
    uint32_t u2 = __float_as_uint(q2), u3 = __float_as_uint(q3);
    // exact residual of the truncated head, then bf16-trunc via perm
    uint32_t r0 = __float_as_uint(q0 - __uint_as_float(u0 & 0xFFFF0000u));
    uint32_t r1 = __float_as_uint(q1 - __uint_as_float(u1 & 0xFFFF0000u));
    uint32_t r2 = __float_as_uint(q2 - __uint_as_float(u2 & 0xFFFF0000u));
    uint32_t r3 = __float_as_uint(q3 - __uint_as_float(u3 & 0xFFFF0000u));
    uint32_t PH0 = pkhi(u0, 0u), PH1 = pkhi(u1, u0), PH2 = pkhi(u2, u1),
             PH3 = pkhi(u3, u2), PH4 = pkhi(0u, u3);
    uint32_t PL0 = pkhi(r0, 0u), PL1 = pkhi(r1, r0), PL2 = pkhi(r2, r1),
             PL3 = pkhi(r3, r2), PL4 = pkhi(0u, r3);
#pragma unroll
    for (int p = 0; p < 4; ++p) {
        bool c0 = (i == 2 * p), c1 = (i == 2 * p + 1), c2 = (i == 2 * p + 2),
             c3 = (i == 2 * p + 3), c4 = (i == 2 * p + 4);
        ah.u[p] = c0 ? PH0 : c1 ? PH1 : c2 ? PH2 : c3 ? PH3 : c4 ? PH4 : 0u;
        al.u[p] = c0 ? PL0 : c1 ? PL1 : c2 ? PL2 : c3 ? PL3 : c4 ? PL4 : 0u;
    }
}

__device__ __forceinline__ void build_silu_frag(const float* __restrict__ xp, Frag& ah, Frag& al) {
    float4 a = *(const float4*)xp;
    float4 b = *(const float4*)(xp + 4);
    float xs[8] = {a.x, a.y, a.z, a.w, b.x, b.y, b.z, b.w};
#pragma unroll
    for (int p = 0; p < 4; ++p) {
        float x0 = xs[p * 2], x1 = xs[p * 2 + 1];
        float v0 = x0 / (1.f + __expf(-x0));
        float v1 = x1 / (1.f + __expf(-x1));
        uint32_t w0 = __float_as_uint(v0), w1 = __float_as_uint(v1);
        uint32_t l0 = __float_as_uint(v0 - __uint_as_float(w0 & 0xFFFF0000u));
        uint32_t l1 = __float_as_uint(v1 - __uint_as_float(w1 & 0xFFFF0000u));
        ah.u[p] = pkhi(w0, w1);
        al.u[p] = pkhi(l0, l1);
    }
}

// ---------------------------------------------------------------------------
__global__ void encode_kernel(const float* __restrict__ x,
                              const float* __restrict__ freq,
                              float* __restrict__ h0) {
    int n = blockIdx.x * blockDim.x + threadIdx.x;
    if (n >= N_PTS) return;
    float xv = x[n];
#pragma unroll
    for (int l = 0; l < 16; ++l) {
        float e = xv * freq[l];
        h0[n * 32 + l]      = sinf(e);
        h0[n * 32 + 16 + l] = cosf(e);
    }
}

// Fold sw*ss (k = f*8+j) and bw (k = 8F+f) into split-bf16 pair, layout
// Wh/Wl[(k>>3)][col][k&7] so fragment reads are 16B/lane-contiguous.
__global__ void prep_kernel(const float* __restrict__ bw,
                            const float* __restrict__ sw,
                            const float* __restrict__ ss,
                            short* __restrict__ Wh, short* __restrict__ Wl, int F) {
    int id = blockIdx.x * blockDim.x + threadIdx.x;
    int K = 9 * F;
    if (id >= K * 256) return;
    int col = id & 255;
    int k   = id >> 8;
    float wv;
    if (k < 8 * F) {
        int f = k >> 3, j = k & 7;
        wv = sw[(col * F + f) * 8 + j] * ss[col * F + f];
    } else {
        int f = k - 8 * F;
        wv = bw[col * F + f];
    }
    uint32_t hh = bf16rne(wv);
    uint32_t ll = bf16rne(wv - bf16tof(hh));
    size_t idx = ((size_t)(k >> 3) * 256 + col) * 8 + (k & 7);
    Wh[idx] = (short)hh;
    Wl[idx] = (short)ll;
}

// ---------------------------------------------------------------------------
// out(N,256) = Aug(h)(N,9F) @ W(9F,256), split-bf16 32x32x16 MFMA, split-K,
// BARRIER-FREE K-loop with W read directly from global (L1/L2-cached).
// Wave (rg, ks): 32 rows, chunks c with c%2==ks.
// A-frag layout (32x32x16): row = lane&31, k = (lane>>5)*8 + j.
// B-frag layout:            col = lane&31, k = (lane>>5)*8 + j.
// C/D layout:               col = lane&31, row = (reg&3)+8*(reg>>2)+4*(lane>>5).
template <int F>
__global__ __launch_bounds__(512, 2)
void layer_mfma(const float* __restrict__ hin,
                const short* __restrict__ Wh, const short* __restrict__ Wl,
                float* __restrict__ out) {
    constexpr int KBC = F / 4;         // basis chunks (8F/32)
    constexpr int KSC = F / 32;        // silu chunks
    constexpr int NC  = KBC + KSC;
    constexpr int NP  = (NC + 1) / 2;  // chunk steps per parity
    __shared__ float red[4][4][1024];  // epilogue scratch, 64 KB

    const int tid  = threadIdx.x;
    const int wv   = tid >> 6;
    const int rg   = wv & 3;           // row-group 0..3
    const int ks   = wv >> 2;          // chunk parity 0..1
    const int lane = tid & 63;
    const int lc   = lane & 31;        // A row / B col within tile
    const int half = lane >> 5;        // k-subgroup
    const int row0 = blockIdx.x * 128;
    const int r    = row0 + rg * 32 + lc;   // this lane's A row
    const float* hrow = hin + (size_t)r * F;

    f32x16 acc[8];
#pragma unroll
    for (int a = 0; a < 8; ++a)
#pragma unroll
        for (int e = 0; e < 16; ++e) acc[a][e] = 0.f;

    // preload x for my first chunk (c0 = ks, always a basis chunk):
    // feature = c*4 + kh*2 + half
    float xreg[2];
#pragma unroll
    for (int kh = 0; kh < 2; ++kh)
        xreg[kh] = hrow[ks * 4 + kh * 2 + half];

    for (int p = 0; p < NP; ++p) {
        const int c = 2 * p + ks;      // my chunk this step
        if (c < NC) {
            // ---- A fragments (registers), one per k-half ----
            Frag ah[2], al[2];
            if (c < KBC) {
                float x0 = xreg[0], x1 = xreg[1];
                if (c + 2 < KBC) {   // prefetch activations for my next chunk
#pragma unroll
                    for (int kh = 0; kh < 2; ++kh)
                        xreg[kh] = hrow[(c + 2) * 4 + kh * 2 + half];
                }
                build_basis_frag(x0, ah[0], al[0]);
                build_basis_frag(x1, ah[1], al[1]);
            } else {
                const int fb = (c - KBC) * 32 + half * 8;
#pragma unroll
                for (int kh = 0; kh < 2; ++kh)
                    build_silu_frag(&hrow[fb + kh * 16], ah[kh], al[kh]);
            }

            // ---- MFMA: product-major ct-groups of 4, W straight from L1/L2 ----
            const short* WHg = Wh + (size_t)c * 8192;
            const short* WLg = Wl + (size_t)c * 8192;
#pragma unroll
            for (int kh = 0; kh < 2; ++kh) {
#pragma unroll
                for (int g = 0; g < 2; ++g) {
                    const int cb  = g * 4;
                    const int ob  = ((kh * 2 + half) * 256 + cb * 32 + lc) * 8;
                    Frag w0, w1, w2, w3;
                    w0.v = *(const short8*)&WHg[ob];
                    w1.v = *(const short8*)&WHg[ob + 256];
                    w2.v = *(const short8*)&WHg[ob + 512];
                    w3.v = *(const short8*)&WHg[ob + 768];
                    Frag v0, v1, v2, v3;
                    v0.v = *(const short8*)&WLg[ob];
                    v1.v = *(const short8*)&WLg[ob + 256];
                    v2.v = *(const short8*)&WLg[ob + 512];
                    v3.v = *(const short8*)&WLg[ob + 768];
                    acc[cb + 0] = __builtin_amdgcn_mfma_f32_32x32x16_bf16(ah[kh].v, w0.v, acc[cb + 0], 0, 0, 0);
                    acc[cb + 1] = __builtin_amdgcn_mfma_f32_32x32x16_bf16(ah[kh].v, w1.v, acc[cb + 1], 0, 0, 0);
                    acc[cb + 2] = __builtin_amdgcn_mfma_f32_32x32x16_bf16(ah[kh].v, w2.v, acc[cb + 2], 0, 0, 0);
                    acc[cb + 3] = __builtin_amdgcn_mfma_f32_32x32x16_bf16(ah[kh].v, w3.v, acc[cb + 3], 0, 0, 0);
                    acc[cb + 0] = __builtin_amdgcn_mfma_f32_32x32x16_bf16(al[kh].v, w0.v, acc[cb + 0], 0, 0, 0);
                    acc[cb + 1] = __builtin_amdgcn_mfma_f32_32x32x16_bf16(al[kh].v, w1.v, acc[cb + 1], 0, 0, 0);
                    acc[cb + 2] = __builtin_amdgcn_mfma_f32_32x32x16_bf16(al[kh].v, w2.v, acc[cb + 2], 0, 0, 0);
                    acc[cb + 3] = __builtin_amdgcn_mfma_f32_32x32x16_bf16(al[kh].v, w3.v, acc[cb + 3], 0, 0, 0);
                    acc[cb + 0] = __builtin_amdgcn_mfma_f32_32x32x16_bf16(ah[kh].v, v0.v, acc[cb + 0], 0, 0, 0);
                    acc[cb + 1] = __builtin_amdgcn_mfma_f32_32x32x16_bf16(ah[kh].v, v1.v, acc[cb + 1], 0, 0, 0);
                    acc[cb + 2] = __builtin_amdgcn_mfma_f32_32x32x16_bf16(ah[kh].v, v2.v, acc[cb + 2], 0, 0, 0);
                    acc[cb + 3] = __builtin_amdgcn_mfma_f32_32x32x16_bf16(ah[kh].v, v3.v, acc[cb + 3], 0, 0, 0);
                }
            }
        }
    }

    // ---- epilogue: 2-pass cross-ks reduction through 64 KB LDS scratch ----
    // Tile layout within red[rg][cti]: e4*256 + lane*4 (16B/lane contiguous).
    // Pass A: ks=1 writes acc[0..3]; ks=0 adds + stores cols 0..127.
    // Pass B: ks=0 writes acc[4..7]; ks=1 adds + stores cols 128..255.
    if (ks == 1) {
#pragma unroll
        for (int cti = 0; cti < 4; ++cti)
#pragma unroll
            for (int e4 = 0; e4 < 4; ++e4) {
                f32x4 v = {acc[cti][e4 * 4 + 0], acc[cti][e4 * 4 + 1],
                           acc[cti][e4 * 4 + 2], acc[cti][e4 * 4 + 3]};
                *(f32x4*)(&red[rg][cti][e4 * 256 + lane * 4]) = v;
            }
    }
    __syncthreads();
    if (ks == 0) {
#pragma unroll
        for (int cti = 0; cti < 4; ++cti) {
            const int colg = cti * 32 + lc;
#pragma unroll
            for (int e4 = 0; e4 < 4; ++e4) {
                f32x4 v = *(const f32x4*)(&red[rg][cti][e4 * 256 + lane * 4]);
#pragma unroll
                for (int j = 0; j < 4; ++j) {
                    const int rgi  = e4 * 4 + j;
                    const int rowg = row0 + rg * 32 + (rgi & 3) + 8 * (rgi >> 2) + 4 * half;
                    out[(size_t)rowg * 256 + colg] = acc[cti][rgi] + v[j];
                }
            }
        }
    }
    __syncthreads();
    if (ks == 0) {
#pragma unroll
        for (int cti = 0; cti < 4; ++cti)
#pragma unroll
            for (int e4 = 0; e4 < 4; ++e4) {
                f32x4 v = {acc[4 + cti][e4 * 4 + 0], acc[4 + cti][e4 * 4 + 1],
                           acc[4 + cti][e4 * 4 + 2], acc[4 + cti][e4 * 4 + 3]};
                *(f32x4*)(&red[rg][cti][e4 * 256 + lane * 4]) = v;
            }
    }
    __syncthreads();
    if (ks == 1) {
#pragma unroll
        for (int cti = 0; cti < 4; ++cti) {
            const int colg = (4 + cti) * 32 + lc;
#pragma unroll
            for (int e4 = 0; e4 < 4; ++e4) {
                f32x4 v = *(const f32x4*)(&red[rg][cti][e4 * 256 + lane * 4]);
#pragma unroll
                for (int j = 0; j < 4; ++j) {
                    const int rgi  = e4 * 4 + j;
                    const int rowg = row0 + rg * 32 + (rgi & 3) + 8 * (rgi >> 2) + 4 * half;
                    out[(size_t)rowg * 256 + colg] = acc[4 + cti][rgi] + v[j];
                }
            }
        }
    }
}

// ---------------------------------------------------------------------------
// Final layer (n_out=1), fp32 wave-reduce.
__device__ __forceinline__ float knotf(int j) { return (float)(j - 3) * 0.4f - 1.0f; }

__device__ __forceinline__ void spline8(float x, float b[8]) {
    float b0[11];
#pragma unroll
    for (int j = 0; j < 11; ++j)
        b0[j] = (x >= knotf(j) && x < knotf(j + 1)) ? 1.0f : 0.0f;
    float b1[10];
#pragma unroll
    for (int j = 0; j < 10; ++j)
        b1[j] = (x - knotf(j)) * (1.0f / (knotf(j + 1) - knotf(j))) * b0[j]
              + (knotf(j + 2) - x) * (1.0f / (knotf(j + 2) - knotf(j + 1))) * b0[j + 1];
    float b2[9];
#pragma unroll
    for (int j = 0; j < 9; ++j)
        b2[j] = (x - knotf(j)) * (1.0f / (knotf(j + 2) - knotf(j))) * b1[j]
              + (knotf(j + 3) - x) * (1.0f / (knotf(j + 3) - knotf(j + 1))) * b1[j + 1];
#pragma unroll
    for (int j = 0; j < 8; ++j)
        b[j]  = (x - knotf(j)) * (1.0f / (knotf(j + 3) - knotf(j))) * b2[j]
              + (knotf(j + 4) - x) * (1.0f / (knotf(j + 4) - knotf(j + 1))) * b2[j + 1];
}

__global__ void layer3_kernel(const float* __restrict__ hin,
                              const float* __restrict__ sw,
                              const float* __restrict__ ss,
                              const float* __restrict__ bw,
                              float* __restrict__ out) {
    int gid  = blockIdx.x * blockDim.x + threadIdx.x;
    int row  = gid >> 6;
    int lane = gid & 63;
    if (row >= N_PTS) return;
    float acc = 0.0f;
#pragma unroll
    for (int it = 0; it < 4; ++it) {
        int f = lane + it * 64;
        float x = hin[(size_t)row * 256 + f];
        float b[8];
        spline8(x, b);
        float dot = 0.0f;
#pragma unroll
        for (int j = 0; j < 8; ++j) dot = fmaf(b[j], sw[f * 8 + j], dot);
        acc = fmaf(dot, ss[f], acc);
        acc = fmaf(x / (1.0f + expf(-x)), bw[f], acc);
    }
#pragma unroll
    for (int off = 32; off > 0; off >>= 1) acc += __shfl_down(acc, off);
    if (lane == 0) out[row] = acc;
}

// ---------------------------------------------------------------------------
// ws layout (bytes)
#define WH0_OFF 0u
#define WL0_OFF (WH0_OFF + 147456u)      // 288*256*2
#define WH1_OFF (WL0_OFF + 147456u)
#define WL1_OFF (WH1_OFF + 1179648u)     // 2304*256*2
#define WH2_OFF (WL1_OFF + 1179648u)
#define WL2_OFF (WH2_OFF + 1179648u)
#define H0_OFF  (WL2_OFF + 1179648u)     // 32768*32*4
#define HA_OFF  (H0_OFF + 4194304u)      // 32768*256*4
#define HB_OFF  (HA_OFF + 33554432u)
// total = 76,316,672 B

extern "C" void kernel_launch(void* const* d_in, const int* in_sizes, int n_in,
                              void* d_out, int out_size, void* d_ws, size_t ws_size,
                              hipStream_t stream) {
    const float* x    = (const float*)d_in[0];
    const float* freq = (const float*)d_in[1];
    const float* bw0  = (const float*)d_in[2];
    const float* sw0  = (const float*)d_in[3];
    const float* ss0  = (const float*)d_in[4];
    const float* bw1  = (const float*)d_in[5];
    const float* sw1  = (const float*)d_in[6];
    const float* ss1  = (const float*)d_in[7];
    const float* bw2  = (const float*)d_in[8];
    const float* sw2  = (const float*)d_in[9];
    const float* ss2  = (const float*)d_in[10];
    const float* bw3  = (const float*)d_in[11];
    const float* sw3  = (const float*)d_in[12];
    const float* ss3  = (const float*)d_in[13];

    char* ws = (char*)d_ws;
    short* Wh0 = (short*)(ws + WH0_OFF);
    short* Wl0 = (short*)(ws + WL0_OFF);
    short* Wh1 = (short*)(ws + WH1_OFF);
    short* Wl1 = (short*)(ws + WL1_OFF);
    short* Wh2 = (short*)(ws + WH2_OFF);
    short* Wl2 = (short*)(ws + WL2_OFF);
    float* h0 = (float*)(ws + H0_OFF);
    float* hA = (float*)(ws + HA_OFF);
    float* hB = (float*)(ws + HB_OFF);
    float* outp = (float*)d_out;

    prep_kernel<<<288, 256, 0, stream>>>(bw0, sw0, ss0, Wh0, Wl0, 32);
    prep_kernel<<<2304, 256, 0, stream>>>(bw1, sw1, ss1, Wh1, Wl1, 256);
    prep_kernel<<<2304, 256, 0, stream>>>(bw2, sw2, ss2, Wh2, Wl2, 256);

    encode_kernel<<<(N_PTS + 255) / 256, 256, 0, stream>>>(x, freq, h0);

    layer_mfma<32><<<N_PTS / 128, 512, 0, stream>>>(h0, Wh0, Wl0, hA);
    layer_mfma<256><<<N_PTS / 128, 512, 0, stream>>>(hA, Wh1, Wl1, hB);
    layer_mfma<256><<<N_PTS / 128, 512, 0, stream>>>(hB, Wh2, Wl2, hA);

    layer3_kernel<<<(N_PTS * 64) / 256, 256, 0, stream>>>(hA, sw3, ss3, bw3, outp);
}

// Round 9
// 363.888 us; speedup vs baseline: 1.2995x; 1.2995x over previous
//
#include <hip/hip_runtime.h>
#include <math.h>
#include <stdint.h>

// ---------------------------------------------------------------------------
// KAN forward, split-bf16 MFMA version, round 12: SGB-pinned MFMA/VALU mix.
//   R10 base restored (LDS-staged W, split-K parity, one __syncthreads/pair —
//   R11's global-W was L2-BW-bound: 256 KB/CU/pair re-read, +47 us).
//   Structural diagnosis: phase-locked waves make MFMA (3072), VALU (2670)
//   and stall (2350) cyc/SIMD/pair strictly ADDITIVE. Fix = intra-wave
//   interleave: builds for chunk c+2 are pipelined (R7 flow) and the whole
//   pair body is ONE branchless block ending in a sched_group_barrier
//   pattern x8 {DS4, VALU6, MFMA2, VALU6, MFMA2, VALU6, MFMA2} so build VALU
//   issues under the 32-cyc MFMA pipe occupancy instead of forming a serial
//   phase. Main loop covers basis-only-build pairs (branchless); remaining
//   pairs (silu builds / guards) take a plain un-pinned tail path.
//   W frags read in 2-ct subgroups (4 live frags, 16 VGPR) for reg headroom.
//   Per-acc product order unchanged (AhWh -> AlWh -> AhWl per kh) => bitwise
//   identical results.
//   Augmented-K GEMM per layer: K = 9F (8 spline bases + 1 silu per feature).
//   W prefolded, split into bf16 hi/lo pair, staged via global_load_lds.
//   3-product split emulation: Ah*Wh + Al*Wh + Ah*Wl  (error ~2^-16 rel).
// ---------------------------------------------------------------------------

#define N_PTS 32768

using short8 = __attribute__((ext_vector_type(8))) short;
using f32x4  = __attribute__((ext_vector_type(4))) float;
using f32x16 = __attribute__((ext_vector_type(16))) float;

union Frag { short8 v; uint32_t u[4]; };

__device__ __forceinline__ uint32_t bf16rne(float f) {
    uint32_t u = __float_as_uint(f);
    return (u + 0x7FFFu + ((u >> 16) & 1u)) >> 16;
}
__device__ __forceinline__ float bf16tof(uint32_t h) { return __uint_as_float(h << 16); }

// pack bf16-trunc(x0) into lo16, bf16-trunc(x1) into hi16 — one v_perm_b32
__device__ __forceinline__ uint32_t pkhi(uint32_t x0, uint32_t x1) {
    return __builtin_amdgcn_perm(x1, x0, 0x07060302u);
}

// async global->LDS, 16B per lane (wave-uniform base + lane*16 semantics)
__device__ __forceinline__ void gld16(const void* g, void* lds) {
    __builtin_amdgcn_global_load_lds(
        (const __attribute__((address_space(1))) void*)(uintptr_t)g,
        (__attribute__((address_space(3))) void*)(uint32_t)(uintptr_t)lds,
        16, 0, 0);
}

// ---------------------------------------------------------------------------
// fast uniform cubic B-spline, trunc-split bf16 fragments.
// t = (x+2.2)/0.4 ; i = floor(t) ; slot j nonzero for j = i-3..i with value
// q_{i-j}.  Pair p (slots 2p,2p+1) selected from 5 packed candidates by i-2p.
__device__ __forceinline__ void build_basis_frag(float x, Frag& ah, Frag& al) {
    float t  = (x + 2.2f) * 2.5f;
    float fl = floorf(t);
    int   i  = (int)fl;
    float w  = t - fl;
    float w2 = w * w, w3 = w2 * w;
    const float s = 1.0f / 6.0f;
    float q0 = w3 * s;                                     // d == 0 (j == i)
    float q1 = (-3.f * w3 + 3.f * w2 + 3.f * w + 1.f) * s; // d == 1
    float q2 = (3.f * w3 - 6.f * w2 + 4.f) * s;            // d == 2
    float omw = 1.f - w;
    float q3 = omw * omw * omw * s;                        // d == 3
    uint32_t u0 = __float_as_uint(q0), u1 = __float_as_uint(q1);
    uint32_t u2 = __float_as_uint(q2), u3 = __float_as_uint(q3);
    // exact residual of the truncated head, then bf16-trunc via perm
    uint32_t r0 = __float_as_uint(q0 - __uint_as_float(u0 & 0xFFFF0000u));
    uint32_t r1 = __float_as_uint(q1 - __uint_as_float(u1 & 0xFFFF0000u));
    uint32_t r2 = __float_as_uint(q2 - __uint_as_float(u2 & 0xFFFF0000u));
    uint32_t r3 = __float_as_uint(q3 - __uint_as_float(u3 & 0xFFFF0000u));
    uint32_t PH0 = pkhi(u0, 0u), PH1 = pkhi(u1, u0), PH2 = pkhi(u2, u1),
             PH3 = pkhi(u3, u2), PH4 = pkhi(0u, u3);
    uint32_t PL0 = pkhi(r0, 0u), PL1 = pkhi(r1, r0), PL2 = pkhi(r2, r1),
             PL3 = pkhi(r3, r2), PL4 = pkhi(0u, r3);
#pragma unroll
    for (int p = 0; p < 4; ++p) {
        bool c0 = (i == 2 * p), c1 = (i == 2 * p + 1), c2 = (i == 2 * p + 2),
             c3 = (i == 2 * p + 3), c4 = (i == 2 * p + 4);
        ah.u[p] = c0 ? PH0 : c1 ? PH1 : c2 ? PH2 : c3 ? PH3 : c4 ? PH4 : 0u;
        al.u[p] = c0 ? PL0 : c1 ? PL1 : c2 ? PL2 : c3 ? PL3 : c4 ? PL4 : 0u;
    }
}

__device__ __forceinline__ void build_silu_frag(const float* __restrict__ xp, Frag& ah, Frag& al) {
    float4 a = *(const float4*)xp;
    float4 b = *(const float4*)(xp + 4);
    float xs[8] = {a.x, a.y, a.z, a.w, b.x, b.y, b.z, b.w};
#pragma unroll
    for (int p = 0; p < 4; ++p) {
        float x0 = xs[p * 2], x1 = xs[p * 2 + 1];
        float v0 = x0 / (1.f + __expf(-x0));
        float v1 = x1 / (1.f + __expf(-x1));
        uint32_t w0 = __float_as_uint(v0), w1 = __float_as_uint(v1);
        uint32_t l0 = __float_as_uint(v0 - __uint_as_float(w0 & 0xFFFF0000u));
        uint32_t l1 = __float_as_uint(v1 - __uint_as_float(w1 & 0xFFFF0000u));
        ah.u[p] = pkhi(w0, w1);
        al.u[p] = pkhi(l0, l1);
    }
}

// ---------------------------------------------------------------------------
__global__ void encode_kernel(const float* __restrict__ x,
                              const float* __restrict__ freq,
                              float* __restrict__ h0) {
    int n = blockIdx.x * blockDim.x + threadIdx.x;
    if (n >= N_PTS) return;
    float xv = x[n];
#pragma unroll
    for (int l = 0; l < 16; ++l) {
        float e = xv * freq[l];
        h0[n * 32 + l]      = sinf(e);
        h0[n * 32 + 16 + l] = cosf(e);
    }
}

// Fold sw*ss (k = f*8+j) and bw (k = 8F+f) into split-bf16 pair, layout
// Wh/Wl[(k>>3)][col][k&7] so fragment reads are ds_read_b128-contiguous and
// chunk staging (32 k x 256 cols = 16 KB) is flat-contiguous.
__global__ void prep_kernel(const float* __restrict__ bw,
                            const float* __restrict__ sw,
                            const float* __restrict__ ss,
                            short* __restrict__ Wh, short* __restrict__ Wl, int F) {
    int id = blockIdx.x * blockDim.x + threadIdx.x;
    int K = 9 * F;
    if (id >= K * 256) return;
    int col = id & 255;
    int k   = id >> 8;
    float wv;
    if (k < 8 * F) {
        int f = k >> 3, j = k & 7;
        wv = sw[(col * F + f) * 8 + j] * ss[col * F + f];
    } else {
        int f = k - 8 * F;
        wv = bw[col * F + f];
    }
    uint32_t hh = bf16rne(wv);
    uint32_t ll = bf16rne(wv - bf16tof(hh));
    size_t idx = ((size_t)(k >> 3) * 256 + col) * 8 + (k & 7);
    Wh[idx] = (short)hh;
    Wl[idx] = (short)ll;
}

// ---------------------------------------------------------------------------
// out(N,256) = Aug(h)(N,9F) @ W(9F,256), split-bf16 32x32x16 MFMA, split-K,
// SGB-interleaved main loop. Wave (rg, ks): 32 rows, chunks c with c%2==ks.
// A-frag layout (32x32x16): row = lane&31, k = (lane>>5)*8 + j.
// B-frag layout:            col = lane&31, k = (lane>>5)*8 + j.
// C/D layout:               col = lane&31, row = (reg&3)+8*(reg>>2)+4*(lane>>5).
template <int F>
__global__ __launch_bounds__(512, 2)
void layer_mfma(const float* __restrict__ hin,
                const short* __restrict__ Wh, const short* __restrict__ Wl,
                float* __restrict__ out) {
    constexpr int KBC   = F / 4;          // basis chunks (8F/32)
    constexpr int KSC   = F / 32;         // silu chunks
    constexpr int NC    = KBC + KSC;
    constexpr int NP    = (NC + 1) / 2;   // chunk pairs
    constexpr int PMAIN = (KBC - 2) / 2;  // pairs with guaranteed-basis builds
    __shared__ short WB[2][2][2][8192];   // [pairbuf][cip][h/l][32k x 256col] = 128 KB

    const int tid  = threadIdx.x;
    const int wv   = tid >> 6;
    const int rg   = wv & 3;           // row-group 0..3
    const int ks   = wv >> 2;          // chunk parity 0..1
    const int lane = tid & 63;
    const int lc   = lane & 31;        // A row / B col within tile
    const int half = lane >> 5;        // k-subgroup
    const int row0 = blockIdx.x * 128;
    const int r    = row0 + rg * 32 + lc;   // this lane's A row
    const float* hrow = hin + (size_t)r * F;

    f32x16 acc[8];
#pragma unroll
    for (int a = 0; a < 8; ++a)
#pragma unroll
        for (int e = 0; e < 16; ++e) acc[a][e] = 0.f;

    // unguarded staging (main loop: chunks always < NC)
    auto stage_pair_u = [&](int p2, int buf) {
#pragma unroll
        for (int cip = 0; cip < 2; ++cip) {
            const size_t gof = (size_t)(2 * p2 + cip) * 8192;
#pragma unroll
            for (int i = 0; i < 2; ++i) {
                int e = tid * 8 + i * 4096;
                gld16(Wh + gof + e, &WB[buf][cip][0][e]);
                gld16(Wl + gof + e, &WB[buf][cip][1][e]);
            }
        }
    };
    // guarded staging (tail)
    auto stage_pair = [&](int p2, int buf) {
#pragma unroll
        for (int cip = 0; cip < 2; ++cip) {
            int c2 = 2 * p2 + cip;
            if (c2 < NC) {
                const size_t gof = (size_t)c2 * 8192;
#pragma unroll
                for (int i = 0; i < 2; ++i) {
                    int e = tid * 8 + i * 4096;
                    gld16(Wh + gof + e, &WB[buf][cip][0][e]);
                    gld16(Wl + gof + e, &WB[buf][cip][1][e]);
                }
            }
        }
    };

    // MFMA block: 2-ct subgroups, product-major; per-acc order AhWh,AlWh,AhWl
    auto do_mfma = [&](const Frag* ah, const Frag* al, int cur) {
        const short* WHp = WB[cur][ks][0];
        const short* WLp = WB[cur][ks][1];
#pragma unroll
        for (int kh = 0; kh < 2; ++kh) {
#pragma unroll
            for (int sg = 0; sg < 4; ++sg) {
                const int cb = sg * 2;
                const int ob = ((kh * 2 + half) * 256 + cb * 32 + lc) * 8;
                Frag w0, w1, v0, v1;
                w0.v = *(const short8*)&WHp[ob];
                w1.v = *(const short8*)&WHp[ob + 256];
                v0.v = *(const short8*)&WLp[ob];
                v1.v = *(const short8*)&WLp[ob + 256];
                acc[cb + 0] = __builtin_amdgcn_mfma_f32_32x32x16_bf16(ah[kh].v, w0.v, acc[cb + 0], 0, 0, 0);
                acc[cb + 1] = __builtin_amdgcn_mfma_f32_32x32x16_bf16(ah[kh].v, w1.v, acc[cb + 1], 0, 0, 0);
                acc[cb + 0] = __builtin_amdgcn_mfma_f32_32x32x16_bf16(al[kh].v, w0.v, acc[cb + 0], 0, 0, 0);
                acc[cb + 1] = __builtin_amdgcn_mfma_f32_32x32x16_bf16(al[kh].v, w1.v, acc[cb + 1], 0, 0, 0);
                acc[cb + 0] = __builtin_amdgcn_mfma_f32_32x32x16_bf16(ah[kh].v, v0.v, acc[cb + 0], 0, 0, 0);
                acc[cb + 1] = __builtin_amdgcn_mfma_f32_32x32x16_bf16(ah[kh].v, v1.v, acc[cb + 1], 0, 0, 0);
            }
        }
    };

    // prologue: stage pair 0; build frags for chunk c0 = ks (basis);
    // prefetch basis inputs for chunk c0+2.
    stage_pair_u(0, 0);
    Frag cah[2], cal[2];
    {
        float x0 = hrow[ks * 4 + half];
        float x1 = hrow[ks * 4 + 2 + half];
        build_basis_frag(x0, cah[0], cal[0]);
        build_basis_frag(x1, cah[1], cal[1]);
    }
    float cinx0 = hrow[(ks + 2) * 4 + half];
    float cinx1 = hrow[(ks + 2) * 4 + 2 + half];
    __syncthreads();

    // ---- main loop: branchless body, SGB-pinned DS/MFMA/VALU interleave ----
    for (int p = 0; p < PMAIN; ++p) {
        const int cur = p & 1;
        stage_pair_u(p + 1, cur ^ 1);

        const int c  = 2 * p + ks;
        const int cf = c + 4;
        const int cfc = (cf < KBC) ? cf : (KBC - 1);   // branchless clamp
        float ninx0 = hrow[cfc * 4 + half];
        float ninx1 = hrow[cfc * 4 + 2 + half];

        Frag nah[2], nal[2];
        build_basis_frag(cinx0, nah[0], nal[0]);
        build_basis_frag(cinx1, nah[1], nal[1]);

        do_mfma(cah, cal, cur);

        // rotate pipeline state (register movs; hide under pattern VALU)
        cah[0] = nah[0]; cah[1] = nah[1];
        cal[0] = nal[0]; cal[1] = nal[1];
        cinx0 = ninx0;   cinx1 = ninx1;

        // schedule pattern: 8 subgroups of {DS4, VALU6, MFMA2, VALU6, MFMA2,
        // VALU6, MFMA2} -> 32 ds_read / 48 MFMA / 144 VALU interleaved.
#pragma unroll
        for (int s8 = 0; s8 < 8; ++s8) {
            __builtin_amdgcn_sched_group_barrier(0x100, 4, 0);  // ds_read
            __builtin_amdgcn_sched_group_barrier(0x002, 6, 0);  // VALU
            __builtin_amdgcn_sched_group_barrier(0x008, 2, 0);  // MFMA
            __builtin_amdgcn_sched_group_barrier(0x002, 6, 0);
            __builtin_amdgcn_sched_group_barrier(0x008, 2, 0);
            __builtin_amdgcn_sched_group_barrier(0x002, 6, 0);
            __builtin_amdgcn_sched_group_barrier(0x008, 2, 0);
        }
        __syncthreads();
    }

    // ---- tail loop: guarded, un-pinned (silu builds / edge chunks) ----
    for (int p = PMAIN; p < NP; ++p) {
        const int cur = p & 1;
        if (p + 1 < NP) stage_pair(p + 1, cur ^ 1);

        const int c = 2 * p + ks;
        if (c < NC) {
            Frag ah[2], al[2];
            if (c < KBC) {
                float x0 = hrow[c * 4 + half];
                float x1 = hrow[c * 4 + 2 + half];
                build_basis_frag(x0, ah[0], al[0]);
                build_basis_frag(x1, ah[1], al[1]);
            } else {
                const int fb = (c - KBC) * 32 + half * 8;
                build_silu_frag(&hrow[fb], ah[0], al[0]);
                build_silu_frag(&hrow[fb + 16], ah[1], al[1]);
            }
            do_mfma(ah, al, cur);
        }
        __syncthreads();
    }

    // ---- cross-ks reduction via LDS (WB reused as 32K-float scratch) ----
    // Tile (rg, ks, cti) = 1024 floats at ((rg*2+ks)*4+cti)*1024; within:
    // e4*256 + lane*4 (contiguous 16B/lane — conflict-free b128 pattern).
    // Wave (rg, ks) writes its partials for the OTHER half's col-tiles, then
    // reads partner's partials for its OWN half, adds, stores to global.
    float* red = (float*)WB;
    {
        float* wp = red + (size_t)((rg * 2 + ks) * 4) * 1024 + lane * 4;
        if (ks == 0) {
#pragma unroll
            for (int cti = 0; cti < 4; ++cti)
#pragma unroll
                for (int e4 = 0; e4 < 4; ++e4) {
                    f32x4 v = {acc[4 + cti][e4 * 4 + 0], acc[4 + cti][e4 * 4 + 1],
                               acc[4 + cti][e4 * 4 + 2], acc[4 + cti][e4 * 4 + 3]};
                    *(f32x4*)(wp + cti * 1024 + e4 * 256) = v;
                }
        } else {
#pragma unroll
            for (int cti = 0; cti < 4; ++cti)
#pragma unroll
                for (int e4 = 0; e4 < 4; ++e4) {
                    f32x4 v = {acc[cti][e4 * 4 + 0], acc[cti][e4 * 4 + 1],
                               acc[cti][e4 * 4 + 2], acc[cti][e4 * 4 + 3]};
                    *(f32x4*)(wp + cti * 1024 + e4 * 256) = v;
                }
        }
    }
    __syncthreads();
    {
        const float* rp = red + (size_t)((rg * 2 + (1 - ks)) * 4) * 1024 + lane * 4;
        if (ks == 0) {
#pragma unroll
            for (int cti = 0; cti < 4; ++cti) {
                const int colg = cti * 32 + lc;
#pragma unroll
                for (int e4 = 0; e4 < 4; ++e4) {
                    f32x4 v = *(const f32x4*)(rp + cti * 1024 + e4 * 256);
#pragma unroll
                    for (int j = 0; j < 4; ++j) {
                        const int rgi  = e4 * 4 + j;
                        const int rowg = row0 + rg * 32 + (rgi & 3) + 8 * (rgi >> 2) + 4 * half;
                        out[(size_t)rowg * 256 + colg] = acc[cti][rgi] + v[j];
                    }
                }
            }
        } else {
#pragma unroll
            for (int cti = 0; cti < 4; ++cti) {
                const int colg = (4 + cti) * 32 + lc;
#pragma unroll
                for (int e4 = 0; e4 < 4; ++e4) {
                    f32x4 v = *(const f32x4*)(rp + cti * 1024 + e4 * 256);
#pragma unroll
                    for (int j = 0; j < 4; ++j) {
                        const int rgi  = e4 * 4 + j;
                        const int rowg = row0 + rg * 32 + (rgi & 3) + 8 * (rgi >> 2) + 4 * half;
                        out[(size_t)rowg * 256 + colg] = acc[4 + cti][rgi] + v[j];
                    }
                }
            }
        }
    }
}

// ---------------------------------------------------------------------------
// Final layer (n_out=1), fp32 wave-reduce.
__device__ __forceinline__ float knotf(int j) { return (float)(j - 3) * 0.4f - 1.0f; }

__device__ __forceinline__ void spline8(float x, float b[8]) {
    float b0[11];
#pragma unroll
    for (int j = 0; j < 11; ++j)
        b0[j] = (x >= knotf(j) && x < knotf(j + 1)) ? 1.0f : 0.0f;
    float b1[10];
#pragma unroll
    for (int j = 0; j < 10; ++j)
        b1[j] = (x - knotf(j)) * (1.0f / (knotf(j + 1) - knotf(j))) * b0[j]
              + (knotf(j + 2) - x) * (1.0f / (knotf(j + 2) - knotf(j + 1))) * b0[j + 1];
    float b2[9];
#pragma unroll
    for (int j = 0; j < 9; ++j)
        b2[j] = (x - knotf(j)) * (1.0f / (knotf(j + 2) - knotf(j))) * b1[j]
              + (knotf(j + 3) - x) * (1.0f / (knotf(j + 3) - knotf(j + 1))) * b1[j + 1];
#pragma unroll
    for (int j = 0; j < 8; ++j)
        b[j]  = (x - knotf(j)) * (1.0f / (knotf(j + 3) - knotf(j))) * b2[j]
              + (knotf(j + 4) - x) * (1.0f / (knotf(j + 4) - knotf(j + 1))) * b2[j + 1];
}

__global__ void layer3_kernel(const float* __restrict__ hin,
                              const float* __restrict__ sw,
                              const float* __restrict__ ss,
                              const float* __restrict__ bw,
                              float* __restrict__ out) {
    int gid  = blockIdx.x * blockDim.x + threadIdx.x;
    int row  = gid >> 6;
    int lane = gid & 63;
    if (row >= N_PTS) return;
    float acc = 0.0f;
#pragma unroll
    for (int it = 0; it < 4; ++it) {
        int f = lane + it * 64;
        float x = hin[(size_t)row * 256 + f];
        float b[8];
        spline8(x, b);
        float dot = 0.0f;
#pragma unroll
        for (int j = 0; j < 8; ++j) dot = fmaf(b[j], sw[f * 8 + j], dot);
        acc = fmaf(dot, ss[f], acc);
        acc = fmaf(x / (1.0f + expf(-x)), bw[f], acc);
    }
#pragma unroll
    for (int off = 32; off > 0; off >>= 1) acc += __shfl_down(acc, off);
    if (lane == 0) out[row] = acc;
}

// ---------------------------------------------------------------------------
// ws layout (bytes)
#define WH0_OFF 0u
#define WL0_OFF (WH0_OFF + 147456u)      // 288*256*2
#define WH1_OFF (WL0_OFF + 147456u)
#define WL1_OFF (WH1_OFF + 1179648u)     // 2304*256*2
#define WH2_OFF (WL1_OFF + 1179648u)
#define WL2_OFF (WH2_OFF + 1179648u)
#define H0_OFF  (WL2_OFF + 1179648u)     // 32768*32*4
#define HA_OFF  (H0_OFF + 4194304u)      // 32768*256*4
#define HB_OFF  (HA_OFF + 33554432u)
// total = 76,316,672 B

extern "C" void kernel_launch(void* const* d_in, const int* in_sizes, int n_in,
                              void* d_out, int out_size, void* d_ws, size_t ws_size,
                              hipStream_t stream) {
    const float* x    = (const float*)d_in[0];
    const float* freq = (const float*)d_in[1];
    const float* bw0  = (const float*)d_in[2];
    const float* sw0  = (const float*)d_in[3];
    const float* ss0  = (const float*)d_in[4];
    const float* bw1  = (const float*)d_in[5];
    const float* sw1  = (const float*)d_in[6];
    const float* ss1  = (const float*)d_in[7];
    const float* bw2  = (const float*)d_in[8];
    const float* sw2  = (const float*)d_in[9];
    const float* ss2  = (const float*)d_in[10];
    const float* bw3  = (const float*)d_in[11];
    const float* sw3  = (const float*)d_in[12];
    const float* ss3  = (const float*)d_in[13];

    char* ws = (char*)d_ws;
    short* Wh0 = (short*)(ws + WH0_OFF);
    short* Wl0 = (short*)(ws + WL0_OFF);
    short* Wh1 = (short*)(ws + WH1_OFF);
    short* Wl1 = (short*)(ws + WL1_OFF);
    short* Wh2 = (short*)(ws + WH2_OFF);
    short* Wl2 = (short*)(ws + WL2_OFF);
    float* h0 = (float*)(ws + H0_OFF);
    float* hA = (float*)(ws + HA_OFF);
    float* hB = (float*)(ws + HB_OFF);
    float* outp = (float*)d_out;

    prep_kernel<<<288, 256, 0, stream>>>(bw0, sw0, ss0, Wh0, Wl0, 32);
    prep_kernel<<<2304, 256, 0, stream>>>(bw1, sw1, ss1, Wh1, Wl1, 256);
    prep_kernel<<<2304, 256, 0, stream>>>(bw2, sw2, ss2, Wh2, Wl2, 256);

    encode_kernel<<<(N_PTS + 255) / 256, 256, 0, stream>>>(x, freq, h0);

    layer_mfma<32><<<N_PTS / 128, 512, 0, stream>>>(h0, Wh0, Wl0, hA);
    layer_mfma<256><<<N_PTS / 128, 512, 0, stream>>>(hA, Wh1, Wl1, hB);
    layer_mfma<256><<<N_PTS / 128, 512, 0, stream>>>(hB, Wh2, Wl2, hA);

    layer3_kernel<<<(N_PTS * 64) / 256, 256, 0, stream>>>(hA, sw3, ss3, bw3, outp);
}